// Round 1
// baseline (2356.780 us; speedup 1.0000x reference)
//
#include <hip/hip_runtime.h>

// GCN 3-layer encoder: x[N,3] -> GCNConv(3,32)+ReLU -> GCNConv(32,64)+ReLU
// -> GCNConv(64,2) -> global_mean_pool over 128 graphs.
// Uses A@(H W) = (A@H)@W to aggregate the narrower side per layer.
// norm folded as: p = dinv*h ; agg[dst] += p[src] ; out = dinv*(agg + p_self).

#define G_GRAPHS 128

__global__ void deg_kernel(const int* __restrict__ dst, float* __restrict__ deg, int E) {
    int e = blockIdx.x * blockDim.x + threadIdx.x;
    if (e < E) atomicAdd(&deg[dst[e]], 1.0f);
}

__global__ void dinv_kernel(float* __restrict__ dinv, int n) {
    int i = blockIdx.x * blockDim.x + threadIdx.x;
    if (i < n) dinv[i] = rsqrtf(dinv[i] + 1.0f);  // +1 self-loop; always >= 1
}

// p1[i] = dinv[i] * x[i]   (N x 3)
__global__ void prescale1(const float* __restrict__ x, const float* __restrict__ dinv,
                          float* __restrict__ p1, int n) {
    int i = blockIdx.x * blockDim.x + threadIdx.x;
    if (i >= n) return;
    float d = dinv[i];
    p1[3 * i + 0] = d * x[3 * i + 0];
    p1[3 * i + 1] = d * x[3 * i + 1];
    p1[3 * i + 2] = d * x[3 * i + 2];
}

// agg1[dst] += p1[src]  (3-wide)
__global__ void scatter1(const int* __restrict__ src, const int* __restrict__ dst,
                         const float* __restrict__ p1, float* __restrict__ agg1, int E) {
    int e = blockIdx.x * blockDim.x + threadIdx.x;
    if (e >= E) return;
    int s = src[e], d = dst[e];
    atomicAdd(&agg1[3 * d + 0], p1[3 * s + 0]);
    atomicAdd(&agg1[3 * d + 1], p1[3 * s + 1]);
    atomicAdd(&agg1[3 * d + 2], p1[3 * s + 2]);
}

// p2[i] = dinv[i] * relu( (dinv[i]*(agg1[i]+p1[i])) @ W1 + b1 )   (N x 32)
__global__ void layer1_out(const float* __restrict__ agg1, const float* __restrict__ p1,
                           const float* __restrict__ dinv, const float* __restrict__ W1,
                           const float* __restrict__ b1, float* __restrict__ p2, int n) {
    __shared__ float w[96];
    __shared__ float b[32];
    for (int t = threadIdx.x; t < 96; t += blockDim.x) w[t] = W1[t];
    for (int t = threadIdx.x; t < 32; t += blockDim.x) b[t] = b1[t];
    __syncthreads();
    int i = blockIdx.x * blockDim.x + threadIdx.x;
    if (i >= n) return;
    float d = dinv[i];
    float s0 = d * (agg1[3 * i + 0] + p1[3 * i + 0]);
    float s1 = d * (agg1[3 * i + 1] + p1[3 * i + 1]);
    float s2 = d * (agg1[3 * i + 2] + p1[3 * i + 2]);
#pragma unroll
    for (int j = 0; j < 32; ++j) {
        float h = fmaf(s0, w[j], fmaf(s1, w[32 + j], fmaf(s2, w[64 + j], b[j])));
        p2[32 * i + j] = d * fmaxf(h, 0.0f);
    }
}

// agg2[dst] += p2[src]  (32-wide, 8 threads/edge, float4 each)
__global__ void scatter2(const int* __restrict__ src, const int* __restrict__ dst,
                         const float* __restrict__ p2, float* __restrict__ agg2, int E) {
    int t = blockIdx.x * blockDim.x + threadIdx.x;
    if (t >= E * 8) return;
    int e = t >> 3;
    int part = t & 7;
    int s = src[e], d = dst[e];
    const float4 v = *reinterpret_cast<const float4*>(p2 + 32 * (long)s + 4 * part);
    float* a = agg2 + 32 * (long)d + 4 * part;
    atomicAdd(a + 0, v.x);
    atomicAdd(a + 1, v.y);
    atomicAdd(a + 2, v.z);
    atomicAdd(a + 3, v.w);
}

// h2 = relu( (dinv*(agg2+p2)) @ W2 + b2 );  p3[i] = dinv[i] * (h2 @ W3)   (N x 2)
__global__ void layer2_out(const float* __restrict__ agg2, const float* __restrict__ p2,
                           const float* __restrict__ dinv, const float* __restrict__ W2,
                           const float* __restrict__ b2, const float* __restrict__ W3,
                           float* __restrict__ p3, int n) {
    __shared__ float w2[32 * 64];
    __shared__ float b2s[64];
    __shared__ float w3[128];
    for (int t = threadIdx.x; t < 32 * 64; t += blockDim.x) w2[t] = W2[t];
    for (int t = threadIdx.x; t < 64; t += blockDim.x) b2s[t] = b2[t];
    for (int t = threadIdx.x; t < 128; t += blockDim.x) w3[t] = W3[t];
    __syncthreads();
    int i = blockIdx.x * blockDim.x + threadIdx.x;
    if (i >= n) return;
    float d = dinv[i];
    float s[32];
#pragma unroll
    for (int c = 0; c < 32; ++c) s[c] = d * (agg2[32 * i + c] + p2[32 * i + c]);
    float a0 = 0.0f, a1 = 0.0f;
#pragma unroll 4
    for (int j = 0; j < 64; ++j) {
        float h = b2s[j];
#pragma unroll
        for (int c = 0; c < 32; ++c) h = fmaf(s[c], w2[c * 64 + j], h);
        h = fmaxf(h, 0.0f);
        a0 = fmaf(h, w3[2 * j + 0], a0);
        a1 = fmaf(h, w3[2 * j + 1], a1);
    }
    p3[2 * i + 0] = d * a0;
    p3[2 * i + 1] = d * a1;
}

// agg3[dst] += p3[src]  (2-wide)
__global__ void scatter3(const int* __restrict__ src, const int* __restrict__ dst,
                         const float* __restrict__ p3, float* __restrict__ agg3, int E) {
    int e = blockIdx.x * blockDim.x + threadIdx.x;
    if (e >= E) return;
    int s = src[e], d = dst[e];
    float2 v = *reinterpret_cast<const float2*>(p3 + 2 * (long)s);
    atomicAdd(&agg3[2 * d + 0], v.x);
    atomicAdd(&agg3[2 * d + 1], v.y);
}

// h3[i] = dinv*(agg3+p3) + b3 ; LDS-accumulate per block into 128 graphs, then
// flush nonzero bins with global atomics (batch is sorted -> ~1-2 bins/block).
__global__ void pool_kernel(const float* __restrict__ agg3, const float* __restrict__ p3,
                            const float* __restrict__ dinv, const int* __restrict__ batch,
                            const float* __restrict__ b3, float* __restrict__ sums,
                            float* __restrict__ cnt, int n) {
    __shared__ float ls[G_GRAPHS * 2];
    __shared__ float lc[G_GRAPHS];
    for (int t = threadIdx.x; t < G_GRAPHS * 2; t += blockDim.x) ls[t] = 0.0f;
    for (int t = threadIdx.x; t < G_GRAPHS; t += blockDim.x) lc[t] = 0.0f;
    __syncthreads();
    int i = blockIdx.x * blockDim.x + threadIdx.x;
    if (i < n) {
        float d = dinv[i];
        float v0 = fmaf(d, agg3[2 * i + 0] + p3[2 * i + 0], b3[0]);
        float v1 = fmaf(d, agg3[2 * i + 1] + p3[2 * i + 1], b3[1]);
        int g = batch[i];
        atomicAdd(&ls[2 * g + 0], v0);
        atomicAdd(&ls[2 * g + 1], v1);
        atomicAdd(&lc[g], 1.0f);
    }
    __syncthreads();
    for (int g = threadIdx.x; g < G_GRAPHS; g += blockDim.x) {
        float c = lc[g];
        if (c != 0.0f) {
            atomicAdd(&sums[2 * g + 0], ls[2 * g + 0]);
            atomicAdd(&sums[2 * g + 1], ls[2 * g + 1]);
            atomicAdd(&cnt[g], c);
        }
    }
}

__global__ void finalize_kernel(const float* __restrict__ sums, const float* __restrict__ cnt,
                                float* __restrict__ out) {
    int g = threadIdx.x;
    if (g < G_GRAPHS) {
        float c = fmaxf(cnt[g], 1.0f);
        out[2 * g + 0] = sums[2 * g + 0] / c;
        out[2 * g + 1] = sums[2 * g + 1] / c;
    }
}

extern "C" void kernel_launch(void* const* d_in, const int* in_sizes, int n_in,
                              void* d_out, int out_size, void* d_ws, size_t ws_size,
                              hipStream_t stream) {
    const float* x    = (const float*)d_in[0];
    const int*   ei   = (const int*)d_in[1];
    const int*   batch= (const int*)d_in[2];
    const float* W1   = (const float*)d_in[3];
    const float* b1   = (const float*)d_in[4];
    const float* W2   = (const float*)d_in[5];
    const float* b2   = (const float*)d_in[6];
    const float* W3   = (const float*)d_in[7];
    const float* b3   = (const float*)d_in[8];
    float* out = (float*)d_out;

    const int n = in_sizes[0] / 3;
    const int E = in_sizes[1] / 2;
    const int* src = ei;
    const int* dst = ei + E;

    // Workspace layout (floats). Zeroed region first.
    float* w = (float*)d_ws;
    float* dinv = w;               // n
    float* agg1 = dinv + n;        // 3n
    float* agg2 = agg1 + 3 * n;    // 32n
    float* agg3 = agg2 + 32 * n;   // 2n
    float* sums = agg3 + 2 * n;    // 2*G
    float* cnt  = sums + 2 * G_GRAPHS;  // G
    float* p1   = cnt + G_GRAPHS;  // 3n
    float* p2   = p1 + 3 * n;      // 32n
    float* p3   = p2 + 32 * n;     // 2n

    size_t zero_bytes = (size_t)(38 * n + 3 * G_GRAPHS) * sizeof(float);
    hipMemsetAsync(d_ws, 0, zero_bytes, stream);

    const int B = 256;
    int gridE  = (E + B - 1) / B;
    int gridN  = (n + B - 1) / B;
    int gridE8 = (E * 8 + B - 1) / B;

    deg_kernel<<<gridE, B, 0, stream>>>(dst, dinv, E);
    dinv_kernel<<<gridN, B, 0, stream>>>(dinv, n);
    prescale1<<<gridN, B, 0, stream>>>(x, dinv, p1, n);
    scatter1<<<gridE, B, 0, stream>>>(src, dst, p1, agg1, E);
    layer1_out<<<gridN, B, 0, stream>>>(agg1, p1, dinv, W1, b1, p2, n);
    scatter2<<<gridE8, B, 0, stream>>>(src, dst, p2, agg2, E);
    layer2_out<<<gridN, B, 0, stream>>>(agg2, p2, dinv, W2, b2, W3, p3, n);
    scatter3<<<gridE, B, 0, stream>>>(src, dst, p3, agg3, E);
    pool_kernel<<<gridN, B, 0, stream>>>(agg3, p3, dinv, batch, b3, sums, cnt, n);
    finalize_kernel<<<1, 128, 0, stream>>>(sums, cnt, out);
}

// Round 3
// 688.657 us; speedup vs baseline: 3.4223x; 3.4223x over previous
//
#include <hip/hip_runtime.h>

// GCN 3-layer encoder, CSR-gather formulation (no f32 atomics).
// h_l = dinv * ( sum_{src->i} p[src] + p[i] ),  p = dinv * (prev features)
// Aggregation always on the narrower side: A@(H W) = (A@H)@W.
// CSR built per launch: deg (int atomics) -> scan -> placement (int atomics).

#define G_GRAPHS 128

// ---- CSR build ------------------------------------------------------------

__global__ void deg_kernel(const int* __restrict__ dst, int* __restrict__ deg, int E) {
    int e = blockIdx.x * blockDim.x + threadIdx.x;
    if (e < E) atomicAdd(&deg[dst[e]], 1);
}

// Block-local inclusive scan of deg -> woff, block totals -> bsum
__global__ void scan1_kernel(const int* __restrict__ deg, int* __restrict__ woff,
                             int* __restrict__ bsum, int n) {
    __shared__ int tmp[256];
    int i = blockIdx.x * 256 + threadIdx.x;
    int v = (i < n) ? deg[i] : 0;
    tmp[threadIdx.x] = v;
    __syncthreads();
    for (int off = 1; off < 256; off <<= 1) {
        int t = (threadIdx.x >= off) ? tmp[threadIdx.x - off] : 0;
        __syncthreads();
        tmp[threadIdx.x] += t;
        __syncthreads();
    }
    if (i < n) woff[i] = tmp[threadIdx.x];
    if (threadIdx.x == 255) bsum[blockIdx.x] = tmp[255];
}

// Single-block inclusive scan of block sums (nb <= 512)
__global__ void scan2_kernel(int* __restrict__ bsum, int nb) {
    __shared__ int tmp[512];
    int v = (threadIdx.x < nb) ? bsum[threadIdx.x] : 0;
    tmp[threadIdx.x] = v;
    __syncthreads();
    for (int off = 1; off < 512; off <<= 1) {
        int t = (threadIdx.x >= off) ? tmp[threadIdx.x - off] : 0;
        __syncthreads();
        tmp[threadIdx.x] += t;
        __syncthreads();
    }
    if (threadIdx.x < nb) bsum[threadIdx.x] = tmp[threadIdx.x];
}

// woff[i] = exclusive_scan(deg)[i]  (in-place: add carry, subtract own deg)
__global__ void scan3_kernel(const int* __restrict__ bsum, const int* __restrict__ deg,
                             int* __restrict__ woff, int n) {
    int i = blockIdx.x * 256 + threadIdx.x;
    if (i >= n) return;
    int carry = (blockIdx.x > 0) ? bsum[blockIdx.x - 1] : 0;
    woff[i] = woff[i] + carry - deg[i];
}

// csr[pos] = src; woff[i] ends at row end (= start + deg)
__global__ void place_kernel(const int* __restrict__ src, const int* __restrict__ dst,
                             int* __restrict__ woff, int* __restrict__ csr, int E) {
    int e = blockIdx.x * blockDim.x + threadIdx.x;
    if (e >= E) return;
    int pos = atomicAdd(&woff[dst[e]], 1);
    csr[pos] = src[e];
}

__global__ void dinv_kernel(const int* __restrict__ deg, float* __restrict__ dinv, int n) {
    int i = blockIdx.x * blockDim.x + threadIdx.x;
    if (i < n) dinv[i] = rsqrtf((float)deg[i] + 1.0f);
}

// ---- Layers ---------------------------------------------------------------

// p1[i] = dinv[i] * x[i]  (N x 3)
__global__ void prescale1(const float* __restrict__ x, const float* __restrict__ dinv,
                          float* __restrict__ p1, int n) {
    int i = blockIdx.x * blockDim.x + threadIdx.x;
    if (i >= n) return;
    float d = dinv[i];
    p1[3 * i + 0] = d * x[3 * i + 0];
    p1[3 * i + 1] = d * x[3 * i + 1];
    p1[3 * i + 2] = d * x[3 * i + 2];
}

// thread/node: gather 3-wide rows, s = dinv*(sum + self), p2 = dinv*relu(s@W1+b1)
__global__ void layer1_fused(const int* __restrict__ csr, const int* __restrict__ woff,
                             const int* __restrict__ deg, const float* __restrict__ p1,
                             const float* __restrict__ dinv, const float* __restrict__ W1,
                             const float* __restrict__ b1, float* __restrict__ p2, int n) {
    __shared__ float w[96];
    __shared__ float b[32];
    for (int t = threadIdx.x; t < 96; t += blockDim.x) w[t] = W1[t];
    for (int t = threadIdx.x; t < 32; t += blockDim.x) b[t] = b1[t];
    __syncthreads();
    int i = blockIdx.x * blockDim.x + threadIdx.x;
    if (i >= n) return;
    int end = woff[i];
    int dg  = deg[i];
    float s0 = 0.f, s1 = 0.f, s2 = 0.f;
    for (int k = end - dg; k < end; ++k) {
        int s = csr[k];
        s0 += p1[3 * s + 0];
        s1 += p1[3 * s + 1];
        s2 += p1[3 * s + 2];
    }
    float d = dinv[i];
    s0 = d * (s0 + p1[3 * i + 0]);
    s1 = d * (s1 + p1[3 * i + 1]);
    s2 = d * (s2 + p1[3 * i + 2]);
#pragma unroll
    for (int j = 0; j < 32; ++j) {
        float h = fmaf(s0, w[j], fmaf(s1, w[32 + j], fmaf(s2, w[64 + j], b[j])));
        p2[32 * (size_t)i + j] = d * fmaxf(h, 0.0f);
    }
}

// wave/node: gather 32-wide rows (8 lanes x float4, 8 edges in flight),
// slot-reduce via shfl_xor, fuse 32->64 relu and 64->2 transform in-wave.
__global__ __launch_bounds__(256) void gather2_layer2(
    const int* __restrict__ csr, const int* __restrict__ woff, const int* __restrict__ deg,
    const float* __restrict__ p2, const float* __restrict__ dinv,
    const float* __restrict__ W2, const float* __restrict__ b2,
    const float* __restrict__ W3, float* __restrict__ p3, int n) {
    __shared__ float w2[32 * 64];
    __shared__ float b2s[64];
    __shared__ float w3[128];
    for (int t = threadIdx.x; t < 32 * 64; t += 256) w2[t] = W2[t];
    if (threadIdx.x < 64)  b2s[threadIdx.x] = b2[threadIdx.x];
    if (threadIdx.x < 128) w3[threadIdx.x] = W3[threadIdx.x];
    __syncthreads();

    int lane = threadIdx.x & 63;
    int i = blockIdx.x * 4 + (threadIdx.x >> 6);
    if (i >= n) return;  // wave-uniform

    int end = woff[i];
    int dg  = deg[i];
    int beg = end - dg;
    int part = lane & 7;   // which float4 of the 32-float row
    int slot = lane >> 3;  // edge slot 0..7
    float4 acc = {0.f, 0.f, 0.f, 0.f};
    for (int k = slot; k < dg; k += 8) {
        int s = csr[beg + k];
        const float4 v = *reinterpret_cast<const float4*>(p2 + 32 * (size_t)s + 4 * part);
        acc.x += v.x; acc.y += v.y; acc.z += v.z; acc.w += v.w;
    }
    // reduce across the 8 edge slots (xor bits 3..5)
#pragma unroll
    for (int m = 8; m <= 32; m <<= 1) {
        acc.x += __shfl_xor(acc.x, m, 64);
        acc.y += __shfl_xor(acc.y, m, 64);
        acc.z += __shfl_xor(acc.z, m, 64);
        acc.w += __shfl_xor(acc.w, m, 64);
    }
    float d = dinv[i];
    {   // add self row, scale by dinv
        const float4 v = *reinterpret_cast<const float4*>(p2 + 32 * (size_t)i + 4 * part);
        acc.x = d * (acc.x + v.x);
        acc.y = d * (acc.y + v.y);
        acc.z = d * (acc.z + v.z);
        acc.w = d * (acc.w + v.w);
    }
    // lane j computes h2[j]; s[c] broadcast from lane c>>2 (parts live on lanes 0..7)
    int j = lane;
    float h = b2s[j];
#pragma unroll
    for (int p = 0; p < 8; ++p) {
        float s0 = __shfl(acc.x, p, 64);
        float s1 = __shfl(acc.y, p, 64);
        float s2 = __shfl(acc.z, p, 64);
        float s3 = __shfl(acc.w, p, 64);
        h = fmaf(s0, w2[(4 * p + 0) * 64 + j], h);
        h = fmaf(s1, w2[(4 * p + 1) * 64 + j], h);
        h = fmaf(s2, w2[(4 * p + 2) * 64 + j], h);
        h = fmaf(s3, w2[(4 * p + 3) * 64 + j], h);
    }
    h = fmaxf(h, 0.0f);
    float a0 = h * w3[2 * j + 0];
    float a1 = h * w3[2 * j + 1];
#pragma unroll
    for (int m = 1; m < 64; m <<= 1) {
        a0 += __shfl_xor(a0, m, 64);
        a1 += __shfl_xor(a1, m, 64);
    }
    if (lane == 0) {
        p3[2 * (size_t)i + 0] = d * a0;
        p3[2 * (size_t)i + 1] = d * a1;
    }
}

// thread/node: gather 2-wide rows, epilogue + mean-pool (LDS bins -> global atomics)
__global__ void layer3_pool(const int* __restrict__ csr, const int* __restrict__ woff,
                            const int* __restrict__ deg, const float* __restrict__ p3,
                            const float* __restrict__ dinv, const int* __restrict__ batch,
                            const float* __restrict__ b3, float* __restrict__ sums,
                            float* __restrict__ cnt, int n) {
    __shared__ float ls[G_GRAPHS * 2];
    __shared__ float lc[G_GRAPHS];
    for (int t = threadIdx.x; t < G_GRAPHS * 2; t += blockDim.x) ls[t] = 0.0f;
    for (int t = threadIdx.x; t < G_GRAPHS; t += blockDim.x) lc[t] = 0.0f;
    __syncthreads();
    int i = blockIdx.x * blockDim.x + threadIdx.x;
    if (i < n) {
        int end = woff[i];
        int dg  = deg[i];
        float a0 = 0.f, a1 = 0.f;
        for (int k = end - dg; k < end; ++k) {
            int s = csr[k];
            a0 += p3[2 * (size_t)s + 0];
            a1 += p3[2 * (size_t)s + 1];
        }
        float d = dinv[i];
        float v0 = fmaf(d, a0 + p3[2 * (size_t)i + 0], b3[0]);
        float v1 = fmaf(d, a1 + p3[2 * (size_t)i + 1], b3[1]);
        int g = batch[i];
        atomicAdd(&ls[2 * g + 0], v0);
        atomicAdd(&ls[2 * g + 1], v1);
        atomicAdd(&lc[g], 1.0f);
    }
    __syncthreads();
    for (int g = threadIdx.x; g < G_GRAPHS; g += blockDim.x) {
        float c = lc[g];
        if (c != 0.0f) {
            atomicAdd(&sums[2 * g + 0], ls[2 * g + 0]);
            atomicAdd(&sums[2 * g + 1], ls[2 * g + 1]);
            atomicAdd(&cnt[g], c);
        }
    }
}

__global__ void finalize_kernel(const float* __restrict__ sums, const float* __restrict__ cnt,
                                float* __restrict__ out) {
    int g = threadIdx.x;
    if (g < G_GRAPHS) {
        float c = fmaxf(cnt[g], 1.0f);
        out[2 * g + 0] = sums[2 * g + 0] / c;
        out[2 * g + 1] = sums[2 * g + 1] / c;
    }
}

// ---- Launch ---------------------------------------------------------------

extern "C" void kernel_launch(void* const* d_in, const int* in_sizes, int n_in,
                              void* d_out, int out_size, void* d_ws, size_t ws_size,
                              hipStream_t stream) {
    const float* x     = (const float*)d_in[0];
    const int*   ei    = (const int*)d_in[1];
    const int*   batch = (const int*)d_in[2];
    const float* W1    = (const float*)d_in[3];
    const float* b1    = (const float*)d_in[4];
    const float* W2    = (const float*)d_in[5];
    const float* b2    = (const float*)d_in[6];
    const float* W3    = (const float*)d_in[7];
    const float* b3    = (const float*)d_in[8];
    float* out = (float*)d_out;

    const int n = in_sizes[0] / 3;
    const int E = in_sizes[1] / 2;
    const int* src = ei;
    const int* dst = ei + E;

    // Workspace layout. Zeroed region first: deg (n int) + sums (2G) + cnt (G).
    int*   deg  = (int*)d_ws;                 // n
    float* sums = (float*)(deg + n);          // 2*G
    float* cnt  = sums + 2 * G_GRAPHS;        // G
    int*   woff = (int*)(cnt + G_GRAPHS);     // n (scan scratch -> row-end after place)
    int*   csr  = woff + n;                   // E
    float* dinv = (float*)(csr + E);          // n
    float* p1   = dinv + n;                   // 3n
    float* p2   = p1 + 3 * n;                 // 32n (16B-aligned for these n,E)
    float* p3   = p2 + 32 * (size_t)n;        // 2n
    int*   bsum = (int*)(p3 + 2 * n);         // <=512

    hipMemsetAsync(d_ws, 0, (size_t)(n + 3 * G_GRAPHS) * 4, stream);

    const int B = 256;
    const int gridE = (E + B - 1) / B;
    const int gridN = (n + B - 1) / B;
    const int nb    = gridN;  // scan blocks (<=512)

    deg_kernel<<<gridE, B, 0, stream>>>(dst, deg, E);
    scan1_kernel<<<nb, B, 0, stream>>>(deg, woff, bsum, n);
    scan2_kernel<<<1, 512, 0, stream>>>(bsum, nb);
    scan3_kernel<<<nb, B, 0, stream>>>(bsum, deg, woff, n);
    dinv_kernel<<<gridN, B, 0, stream>>>(deg, dinv, n);
    place_kernel<<<gridE, B, 0, stream>>>(src, dst, woff, csr, E);
    prescale1<<<gridN, B, 0, stream>>>(x, dinv, p1, n);
    layer1_fused<<<gridN, B, 0, stream>>>(csr, woff, deg, p1, dinv, W1, b1, p2, n);
    gather2_layer2<<<(n + 3) / 4, 256, 0, stream>>>(csr, woff, deg, p2, dinv, W2, b2, W3, p3, n);
    layer3_pool<<<gridN, B, 0, stream>>>(csr, woff, deg, p3, dinv, batch, b3, sums, cnt, n);
    finalize_kernel<<<1, 128, 0, stream>>>(sums, cnt, out);
}

// Round 4
// 549.465 us; speedup vs baseline: 4.2892x; 1.2533x over previous
//
#include <hip/hip_runtime.h>

// GCN 3-layer encoder, CSR-gather formulation (no f32 atomics).
// h_l = dinv * ( sum_{src->i} p[src] + p[i] ),  p = dinv * (prev features)
// Aggregation always on the narrower side: A@(H W) = (A@H)@W.
// CSR built per launch: deg (int atomics) -> scan -> multi-pass placement.
// Placement is swept in 4096-node dst-ranges so the active CSR write window
// (~512 KB) stays L2-resident and rows fill whole cache lines before
// writeback (round-3 counter evidence: single-pass had 15x write amp).

#define G_GRAPHS 128
#define PASS_SHIFT 12  // 4096 nodes per placement pass

// ---- CSR build ------------------------------------------------------------

__global__ void deg_kernel(const int* __restrict__ dst, int* __restrict__ deg, int E) {
    int e = blockIdx.x * blockDim.x + threadIdx.x;
    if (e < E) atomicAdd(&deg[dst[e]], 1);
}

// Block-local inclusive scan of deg -> woff, block totals -> bsum
__global__ void scan1_kernel(const int* __restrict__ deg, int* __restrict__ woff,
                             int* __restrict__ bsum, int n) {
    __shared__ int tmp[256];
    int i = blockIdx.x * 256 + threadIdx.x;
    int v = (i < n) ? deg[i] : 0;
    tmp[threadIdx.x] = v;
    __syncthreads();
    for (int off = 1; off < 256; off <<= 1) {
        int t = (threadIdx.x >= off) ? tmp[threadIdx.x - off] : 0;
        __syncthreads();
        tmp[threadIdx.x] += t;
        __syncthreads();
    }
    if (i < n) woff[i] = tmp[threadIdx.x];
    if (threadIdx.x == 255) bsum[blockIdx.x] = tmp[255];
}

// Single-block inclusive scan of block sums (nb <= 512)
__global__ void scan2_kernel(int* __restrict__ bsum, int nb) {
    __shared__ int tmp[512];
    int v = (threadIdx.x < nb) ? bsum[threadIdx.x] : 0;
    tmp[threadIdx.x] = v;
    __syncthreads();
    for (int off = 1; off < 512; off <<= 1) {
        int t = (threadIdx.x >= off) ? tmp[threadIdx.x - off] : 0;
        __syncthreads();
        tmp[threadIdx.x] += t;
        __syncthreads();
    }
    if (threadIdx.x < nb) bsum[threadIdx.x] = tmp[threadIdx.x];
}

// woff[i] = exclusive_scan(deg)[i]; also dinv[i] and p1[i] = dinv*x[i] (fused)
__global__ void scan3_fused(const int* __restrict__ bsum, const int* __restrict__ deg,
                            int* __restrict__ woff, const float* __restrict__ x,
                            float* __restrict__ dinv, float* __restrict__ p1, int n) {
    int i = blockIdx.x * 256 + threadIdx.x;
    if (i >= n) return;
    int carry = (blockIdx.x > 0) ? bsum[blockIdx.x - 1] : 0;
    int dg = deg[i];
    woff[i] = woff[i] + carry - dg;
    float di = rsqrtf((float)dg + 1.0f);
    dinv[i] = di;
    p1[3 * i + 0] = di * x[3 * i + 0];
    p1[3 * i + 1] = di * x[3 * i + 1];
    p1[3 * i + 2] = di * x[3 * i + 2];
}

// Multi-pass placement: thread keeps its edge in registers, writes only in the
// pass owning its dst range. Raw s_barrier (no vmcnt drain needed: no
// intra-block data dependence) keeps the block's waves sweeping in phase.
__global__ void place_mp_kernel(const int* __restrict__ src, const int* __restrict__ dst,
                                int* __restrict__ woff, int* __restrict__ csr,
                                int E, int npass) {
    int e = blockIdx.x * blockDim.x + threadIdx.x;
    int d = -1, s = 0;
    if (e < E) { d = dst[e]; s = src[e]; }
    int myp = d >> PASS_SHIFT;  // -1 for inactive lanes: never matches
    for (int p = 0; p < npass; ++p) {
        if (p == myp) {
            int pos = atomicAdd(&woff[d], 1);
            csr[pos] = s;
        }
        __builtin_amdgcn_s_barrier();
    }
}

// ---- Layers ---------------------------------------------------------------

// thread/node: gather 3-wide rows, s = dinv*(sum + self), p2 = dinv*relu(s@W1+b1)
__global__ void layer1_fused(const int* __restrict__ csr, const int* __restrict__ woff,
                             const int* __restrict__ deg, const float* __restrict__ p1,
                             const float* __restrict__ dinv, const float* __restrict__ W1,
                             const float* __restrict__ b1, float* __restrict__ p2, int n) {
    __shared__ float w[96];
    __shared__ float b[32];
    for (int t = threadIdx.x; t < 96; t += blockDim.x) w[t] = W1[t];
    for (int t = threadIdx.x; t < 32; t += blockDim.x) b[t] = b1[t];
    __syncthreads();
    int i = blockIdx.x * blockDim.x + threadIdx.x;
    if (i >= n) return;
    int end = woff[i];
    int dg  = deg[i];
    float s0 = 0.f, s1 = 0.f, s2 = 0.f;
    for (int k = end - dg; k < end; ++k) {
        int s = csr[k];
        s0 += p1[3 * s + 0];
        s1 += p1[3 * s + 1];
        s2 += p1[3 * s + 2];
    }
    float d = dinv[i];
    s0 = d * (s0 + p1[3 * i + 0]);
    s1 = d * (s1 + p1[3 * i + 1]);
    s2 = d * (s2 + p1[3 * i + 2]);
#pragma unroll
    for (int j = 0; j < 32; ++j) {
        float h = fmaf(s0, w[j], fmaf(s1, w[32 + j], fmaf(s2, w[64 + j], b[j])));
        p2[32 * (size_t)i + j] = d * fmaxf(h, 0.0f);
    }
}

// wave/node: gather 32-wide rows (8 lanes x float4, 8 edges in flight),
// slot-reduce via shfl_xor, fuse 32->64 relu and 64->2 transform in-wave.
__global__ __launch_bounds__(256) void gather2_layer2(
    const int* __restrict__ csr, const int* __restrict__ woff, const int* __restrict__ deg,
    const float* __restrict__ p2, const float* __restrict__ dinv,
    const float* __restrict__ W2, const float* __restrict__ b2,
    const float* __restrict__ W3, float* __restrict__ p3, int n) {
    __shared__ float w2[32 * 64];
    __shared__ float b2s[64];
    __shared__ float w3[128];
    for (int t = threadIdx.x; t < 32 * 64; t += 256) w2[t] = W2[t];
    if (threadIdx.x < 64)  b2s[threadIdx.x] = b2[threadIdx.x];
    if (threadIdx.x < 128) w3[threadIdx.x] = W3[threadIdx.x];
    __syncthreads();

    int lane = threadIdx.x & 63;
    int i = blockIdx.x * 4 + (threadIdx.x >> 6);
    if (i >= n) return;  // wave-uniform

    int end = woff[i];
    int dg  = deg[i];
    int beg = end - dg;
    int part = lane & 7;   // which float4 of the 32-float row
    int slot = lane >> 3;  // edge slot 0..7
    float4 acc = {0.f, 0.f, 0.f, 0.f};
    for (int k = slot; k < dg; k += 8) {
        int s = csr[beg + k];
        const float4 v = *reinterpret_cast<const float4*>(p2 + 32 * (size_t)s + 4 * part);
        acc.x += v.x; acc.y += v.y; acc.z += v.z; acc.w += v.w;
    }
    // reduce across the 8 edge slots (xor bits 3..5)
#pragma unroll
    for (int m = 8; m <= 32; m <<= 1) {
        acc.x += __shfl_xor(acc.x, m, 64);
        acc.y += __shfl_xor(acc.y, m, 64);
        acc.z += __shfl_xor(acc.z, m, 64);
        acc.w += __shfl_xor(acc.w, m, 64);
    }
    float d = dinv[i];
    {   // add self row, scale by dinv
        const float4 v = *reinterpret_cast<const float4*>(p2 + 32 * (size_t)i + 4 * part);
        acc.x = d * (acc.x + v.x);
        acc.y = d * (acc.y + v.y);
        acc.z = d * (acc.z + v.z);
        acc.w = d * (acc.w + v.w);
    }
    // lane j computes h2[j]; s[c] broadcast from lane c>>2 (parts live on lanes 0..7)
    int j = lane;
    float h = b2s[j];
#pragma unroll
    for (int p = 0; p < 8; ++p) {
        float s0 = __shfl(acc.x, p, 64);
        float s1 = __shfl(acc.y, p, 64);
        float s2 = __shfl(acc.z, p, 64);
        float s3 = __shfl(acc.w, p, 64);
        h = fmaf(s0, w2[(4 * p + 0) * 64 + j], h);
        h = fmaf(s1, w2[(4 * p + 1) * 64 + j], h);
        h = fmaf(s2, w2[(4 * p + 2) * 64 + j], h);
        h = fmaf(s3, w2[(4 * p + 3) * 64 + j], h);
    }
    h = fmaxf(h, 0.0f);
    float a0 = h * w3[2 * j + 0];
    float a1 = h * w3[2 * j + 1];
#pragma unroll
    for (int m = 1; m < 64; m <<= 1) {
        a0 += __shfl_xor(a0, m, 64);
        a1 += __shfl_xor(a1, m, 64);
    }
    if (lane == 0) {
        p3[2 * (size_t)i + 0] = d * a0;
        p3[2 * (size_t)i + 1] = d * a1;
    }
}

// thread/node: gather 2-wide rows, epilogue + mean-pool (LDS bins -> global atomics)
__global__ void layer3_pool(const int* __restrict__ csr, const int* __restrict__ woff,
                            const int* __restrict__ deg, const float* __restrict__ p3,
                            const float* __restrict__ dinv, const int* __restrict__ batch,
                            const float* __restrict__ b3, float* __restrict__ sums,
                            float* __restrict__ cnt, int n) {
    __shared__ float ls[G_GRAPHS * 2];
    __shared__ float lc[G_GRAPHS];
    for (int t = threadIdx.x; t < G_GRAPHS * 2; t += blockDim.x) ls[t] = 0.0f;
    for (int t = threadIdx.x; t < G_GRAPHS; t += blockDim.x) lc[t] = 0.0f;
    __syncthreads();
    int i = blockIdx.x * blockDim.x + threadIdx.x;
    if (i < n) {
        int end = woff[i];
        int dg  = deg[i];
        float a0 = 0.f, a1 = 0.f;
        for (int k = end - dg; k < end; ++k) {
            int s = csr[k];
            a0 += p3[2 * (size_t)s + 0];
            a1 += p3[2 * (size_t)s + 1];
        }
        float d = dinv[i];
        float v0 = fmaf(d, a0 + p3[2 * (size_t)i + 0], b3[0]);
        float v1 = fmaf(d, a1 + p3[2 * (size_t)i + 1], b3[1]);
        int g = batch[i];
        atomicAdd(&ls[2 * g + 0], v0);
        atomicAdd(&ls[2 * g + 1], v1);
        atomicAdd(&lc[g], 1.0f);
    }
    __syncthreads();
    for (int g = threadIdx.x; g < G_GRAPHS; g += blockDim.x) {
        float c = lc[g];
        if (c != 0.0f) {
            atomicAdd(&sums[2 * g + 0], ls[2 * g + 0]);
            atomicAdd(&sums[2 * g + 1], ls[2 * g + 1]);
            atomicAdd(&cnt[g], c);
        }
    }
}

__global__ void finalize_kernel(const float* __restrict__ sums, const float* __restrict__ cnt,
                                float* __restrict__ out) {
    int g = threadIdx.x;
    if (g < G_GRAPHS) {
        float c = fmaxf(cnt[g], 1.0f);
        out[2 * g + 0] = sums[2 * g + 0] / c;
        out[2 * g + 1] = sums[2 * g + 1] / c;
    }
}

// ---- Launch ---------------------------------------------------------------

extern "C" void kernel_launch(void* const* d_in, const int* in_sizes, int n_in,
                              void* d_out, int out_size, void* d_ws, size_t ws_size,
                              hipStream_t stream) {
    const float* x     = (const float*)d_in[0];
    const int*   ei    = (const int*)d_in[1];
    const int*   batch = (const int*)d_in[2];
    const float* W1    = (const float*)d_in[3];
    const float* b1    = (const float*)d_in[4];
    const float* W2    = (const float*)d_in[5];
    const float* b2    = (const float*)d_in[6];
    const float* W3    = (const float*)d_in[7];
    const float* b3    = (const float*)d_in[8];
    float* out = (float*)d_out;

    const int n = in_sizes[0] / 3;
    const int E = in_sizes[1] / 2;
    const int* src = ei;
    const int* dst = ei + E;

    // Workspace layout. Zeroed region first: deg (n int) + sums (2G) + cnt (G).
    int*   deg  = (int*)d_ws;                 // n
    float* sums = (float*)(deg + n);          // 2*G
    float* cnt  = sums + 2 * G_GRAPHS;        // G
    int*   woff = (int*)(cnt + G_GRAPHS);     // n (scan scratch -> row-end after place)
    int*   csr  = woff + n;                   // E
    float* dinv = (float*)(csr + E);          // n
    float* p1   = dinv + n;                   // 3n
    float* p2   = p1 + 3 * n;                 // 32n (16B-aligned for these n,E)
    float* p3   = p2 + 32 * (size_t)n;        // 2n
    int*   bsum = (int*)(p3 + 2 * n);         // <=512

    hipMemsetAsync(d_ws, 0, (size_t)(n + 3 * G_GRAPHS) * 4, stream);

    const int B = 256;
    const int gridE = (E + B - 1) / B;
    const int gridN = (n + B - 1) / B;
    const int nb    = gridN;  // scan blocks (<=512)
    const int npass = (n + (1 << PASS_SHIFT) - 1) >> PASS_SHIFT;

    deg_kernel<<<gridE, B, 0, stream>>>(dst, deg, E);
    scan1_kernel<<<nb, B, 0, stream>>>(deg, woff, bsum, n);
    scan2_kernel<<<1, 512, 0, stream>>>(bsum, nb);
    scan3_fused<<<nb, B, 0, stream>>>(bsum, deg, woff, x, dinv, p1, n);
    place_mp_kernel<<<gridE, B, 0, stream>>>(src, dst, woff, csr, E, npass);
    layer1_fused<<<gridN, B, 0, stream>>>(csr, woff, deg, p1, dinv, W1, b1, p2, n);
    gather2_layer2<<<(n + 3) / 4, 256, 0, stream>>>(csr, woff, deg, p2, dinv, W2, b2, W3, p3, n);
    layer3_pool<<<gridN, B, 0, stream>>>(csr, woff, deg, p3, dinv, batch, b3, sums, cnt, n);
    finalize_kernel<<<1, 128, 0, stream>>>(sums, cnt, out);
}